// Round 3
// baseline (3847.430 us; speedup 1.0000x reference)
//
#include <hip/hip_runtime.h>
#include <hip/hip_bf16.h>

#define BB 8192
#define TT 5
#define FF 923
#define HH 64
#define NG 256   // 4*H
#define KI 1910  // 923 (x_c) + 923 (m) + 64 (h)

#define OUT_IMP ((size_t)1)
#define OUT_DEC ((size_t)1 + (size_t)BB*TT*FF)

// workspace layout (bytes)
#define H_OFF      ((size_t)256)
#define C_OFF      (H_OFF + (size_t)BB*HH*4)
#define YH_OFF     (C_OFF + (size_t)BB*HH*4)
#define GATES_OFF  (YH_OFF + (size_t)BB*2*4)
#define ENCATT_OFF (GATES_OFF + (size_t)BB*NG*4)
#define ENCW_OFF   (ENCATT_OFF + (size_t)BB*TT*HH*4)
#define ENCOUT_OFF (ENCW_OFF + (size_t)BB*TT*NG*4)
#define ZERO_BYTES (C_OFF + (size_t)BB*HH*4)   // acc + h + c

__device__ __forceinline__ float sigm(float x){ return 1.0f/(1.0f+expf(-x)); }
__device__ __forceinline__ float rnd6(float x){ return rintf(x*1.0e6f)/1.0e6f; }

__device__ __forceinline__ void acc2_block(float s1, float s2, double* a1, double* a2){
  #pragma unroll
  for (int off = 32; off > 0; off >>= 1){
    s1 += __shfl_xor(s1, off, 64);
    s2 += __shfl_xor(s2, off, 64);
  }
  __shared__ float r1[4], r2[4];
  int tid = threadIdx.x;
  if ((tid & 63) == 0){ r1[tid>>6] = s1; r2[tid>>6] = s2; }
  __syncthreads();
  if (tid == 0){
    atomicAdd(a1, (double)r1[0]+(double)r1[1]+(double)r1[2]+(double)r1[3]);
    atomicAdd(a2, (double)r2[0]+(double)r2[1]+(double)r2[2]+(double)r2[3]);
  }
}

// ---------------- K1: h *= exp(-relu(deltas_t @ td_W^T + td_b)) ----------------
// BM=32 rows, N=64, BK=32; grid B/32, 256 thr; each thread 2 rows x 4 cols
__global__ __launch_bounds__(256) void k_gamma(
    const float* __restrict__ deltas, const float* __restrict__ tdW,
    const float* __restrict__ tdb, float* __restrict__ h, int t)
{
  __shared__ __align__(16) float As[32][36];   // [k][row]
  __shared__ __align__(16) float Ws[32][68];   // [k][j]
  int tid = threadIdx.x;
  int b0 = blockIdx.x*32;
  int lk = tid & 7, lr = tid >> 3;   // lk 0..7, lr 0..31
  int tx = tid & 15, ty = tid >> 4;  // cols tx*4, rows ty*2
  float acc[2][4] = {};
  for (int k0 = 0; k0 < FF; k0 += 32) {
    #pragma unroll
    for (int q = 0; q < 4; ++q) {
      int k = lk + 8*q, gk = k0 + k;
      As[k][lr] = (gk < FF) ? deltas[((size_t)(b0+lr)*TT + t)*FF + gk] : 0.0f;
    }
    #pragma unroll
    for (int rp = 0; rp < 2; ++rp) {
      int j = lr + 32*rp;
      #pragma unroll
      for (int q = 0; q < 4; ++q) {
        int k = lk + 8*q, gk = k0 + k;
        Ws[k][j] = (gk < FF) ? tdW[(size_t)j*FF + gk] : 0.0f;
      }
    }
    __syncthreads();
    for (int kk = 0; kk < 32; ++kk) {
      float2 a = *(const float2*)&As[kk][ty*2];
      float4 w = *(const float4*)&Ws[kk][tx*4];
      float av[2] = {a.x, a.y};
      float wv[4] = {w.x, w.y, w.z, w.w};
      #pragma unroll
      for (int i = 0; i < 2; ++i)
        #pragma unroll
        for (int j = 0; j < 4; ++j)
          acc[i][j] = fmaf(av[i], wv[j], acc[i][j]);
    }
    __syncthreads();
  }
  #pragma unroll
  for (int i = 0; i < 2; ++i)
    #pragma unroll
    for (int j = 0; j < 4; ++j) {
      int col = tx*4 + j;
      float g = expf(-fmaxf(acc[i][j] + tdb[col], 0.0f));
      h[(size_t)(b0 + ty*2 + i)*HH + col] *= g;
    }
}

// ---------------- K2: x_h & enc, x_c -> out, enc -> bf16, x_loss partials ----------------
// BM=64 rows, BN=64 cols, K=64; grid (B/64, 15)
__global__ __launch_bounds__(256) void k_xh_enc(
    const float* __restrict__ values, const float* __restrict__ masks,
    const float* __restrict__ histW, const float* __restrict__ histb,
    const float* __restrict__ encWt, const float* __restrict__ encb,
    const float* __restrict__ h, float* __restrict__ out,
    __hip_bfloat16* __restrict__ encout, double* __restrict__ acc, int t)
{
  __shared__ __align__(16) float hs[64][68];   // [k][row]
  __shared__ __align__(16) float W1[64][68];   // [k][col]
  __shared__ __align__(16) float W2[64][68];
  int tid = threadIdx.x;
  int b0 = blockIdx.x*64;
  int c0 = blockIdx.y*64;
  for (int p = 0; p < 16; ++p) {
    int idx = tid + p*256;
    int r = idx >> 6, k = idx & 63;
    hs[k][r] = h[(size_t)(b0+r)*HH + k];
    int cc = c0 + r;
    W1[k][r] = (cc < FF) ? histW[(size_t)cc*HH + k] : 0.0f;
    W2[k][r] = (cc < FF) ? encWt[(size_t)cc*HH + k] : 0.0f;
  }
  __syncthreads();
  int tx = tid & 15, ty = tid >> 4;
  float a1[4][4] = {}, a2[4][4] = {};
  for (int k = 0; k < 64; ++k) {
    float4 av4 = *(const float4*)&hs[k][ty*4];
    float4 w1v = *(const float4*)&W1[k][tx*4];
    float4 w2v = *(const float4*)&W2[k][tx*4];
    float av[4] = {av4.x, av4.y, av4.z, av4.w};
    float w1a[4] = {w1v.x, w1v.y, w1v.z, w1v.w};
    float w2a[4] = {w2v.x, w2v.y, w2v.z, w2v.w};
    #pragma unroll
    for (int i = 0; i < 4; ++i)
      #pragma unroll
      for (int j = 0; j < 4; ++j) {
        a1[i][j] = fmaf(av[i], w1a[j], a1[i][j]);
        a2[i][j] = fmaf(av[i], w2a[j], a2[i][j]);
      }
  }
  float s1 = 0.0f, sm = 0.0f;
  #pragma unroll
  for (int i = 0; i < 4; ++i)
    #pragma unroll
    for (int j = 0; j < 4; ++j) {
      int col = c0 + tx*4 + j;
      int row = b0 + ty*4 + i;
      if (col < FF) {
        float xh = a1[i][j] + histb[col];
        size_t off = ((size_t)row*TT + t)*FF + col;
        float x = values[off], m = masks[off];
        float xc = m*x + (1.0f - m)*xh;
        out[OUT_IMP + off] = rnd6(xc);
        float e = tanhf(a2[i][j] + encb[col]) * m;
        encout[off] = __float2bfloat16(e);
        float d = x - xh;
        s1 += m*d*d;
        sm += m;
      }
    }
  acc2_block(s1, sm, &acc[t], &acc[5+t]);
}

// ---------------- K3a: encoder LSTM gates GEMM: B x 1910 -> 256 ----------------
// BM=64, BN=128, BK=32; grid (B/64, 2); each thread 8 rows x 4 cols
__global__ __launch_bounds__(256) void k_gates(
    const float* __restrict__ out, const float* __restrict__ masks,
    const float* __restrict__ h, const float* __restrict__ Wih,
    const float* __restrict__ Whh, const float* __restrict__ bias,
    float* __restrict__ gates, int t)
{
  __shared__ __align__(16) float As[32][68];    // [k][row 0..63]
  __shared__ __align__(16) float Ws[32][132];   // [k][col 0..127]
  int tid = threadIdx.x;
  int b0 = blockIdx.x*64;
  int c0 = blockIdx.y*128;
  int lk = tid & 7, lr = tid >> 3;
  int tx = tid & 31, ty = tid >> 5;
  float acc[8][4] = {};
  for (int k0 = 0; k0 < KI; k0 += 32) {
    #pragma unroll
    for (int rp = 0; rp < 2; ++rp) {
      int r = lr + 32*rp;
      int row = b0 + r;
      #pragma unroll
      for (int q = 0; q < 4; ++q) {
        int kg = k0 + lk + 8*q;
        float v = 0.0f;
        if (kg < FF)          v = out[OUT_IMP + ((size_t)row*TT + t)*FF + kg];
        else if (kg < 2*FF)   v = masks[((size_t)row*TT + t)*FF + (kg - FF)];
        else if (kg < KI)     v = h[(size_t)row*HH + (kg - 2*FF)];
        As[lk + 8*q][r] = v;
      }
    }
    #pragma unroll
    for (int cp = 0; cp < 4; ++cp) {
      int cl = lr + 32*cp;
      int cc = c0 + cl;
      #pragma unroll
      for (int q = 0; q < 4; ++q) {
        int kg = k0 + lk + 8*q;
        float v = 0.0f;
        if (kg < 2*FF)        v = Wih[(size_t)cc*(2*FF) + kg];
        else if (kg < KI)     v = Whh[(size_t)cc*HH + (kg - 2*FF)];
        Ws[lk + 8*q][cl] = v;
      }
    }
    __syncthreads();
    for (int kk = 0; kk < 32; ++kk) {
      float4 a0 = *(const float4*)&As[kk][ty*8];
      float4 a1v = *(const float4*)&As[kk][ty*8 + 4];
      float4 w = *(const float4*)&Ws[kk][tx*4];
      float av[8] = {a0.x,a0.y,a0.z,a0.w,a1v.x,a1v.y,a1v.z,a1v.w};
      float wv[4] = {w.x,w.y,w.z,w.w};
      #pragma unroll
      for (int i = 0; i < 8; ++i)
        #pragma unroll
        for (int j = 0; j < 4; ++j)
          acc[i][j] = fmaf(av[i], wv[j], acc[i][j]);
    }
    __syncthreads();
  }
  #pragma unroll
  for (int i = 0; i < 8; ++i) {
    int row = b0 + ty*8 + i;
    int cb = c0 + tx*4;
    float4 r4 = {acc[i][0] + bias[cb], acc[i][1] + bias[cb+1],
                 acc[i][2] + bias[cb+2], acc[i][3] + bias[cb+3]};
    *(float4*)&gates[(size_t)row*NG + cb] = r4;
  }
}

// ---------------- K3b: LSTM pointwise update ----------------
__global__ __launch_bounds__(256) void k_lstm(
    const float* __restrict__ gates, float* __restrict__ h, float* __restrict__ c)
{
  int idx = blockIdx.x*256 + threadIdx.x;
  int b = idx >> 6, u = idx & 63;
  const float* g = gates + (size_t)b*NG;
  float gi = g[u], gf = g[64+u], gg = g[128+u], go = g[192+u];
  float cn = sigm(gf)*c[idx] + sigm(gi)*tanhf(gg);
  float hn = sigm(go)*tanhf(cn);
  c[idx] = cn;
  h[idx] = hn;
}

// ---------------- K4: projection GEMM (B*T) x 923 -> 320 (256 decW | 64 att) ----------------
// BM=128, BN=64, BK=32; grid (320, 5); each thread 8 rows x 4 cols
__global__ __launch_bounds__(256) void k_proj(
    const __hip_bfloat16* __restrict__ encout,
    const float* __restrict__ decWih, const float* __restrict__ attW,
    const float* __restrict__ attb,
    float* __restrict__ encWp, float* __restrict__ encA)
{
  __shared__ __align__(16) float As[32][136];  // [k][row 0..127]
  __shared__ __align__(16) float Ws[32][68];   // [k][col 0..63]
  int tid = threadIdx.x;
  int r0 = blockIdx.x*128;
  int c0 = blockIdx.y*64;
  int lk = tid & 7, lr = tid >> 3;
  int tx = tid & 15, ty = tid >> 4;
  float acc[8][4] = {};
  for (int k0 = 0; k0 < FF; k0 += 32) {
    #pragma unroll
    for (int rp = 0; rp < 4; ++rp) {
      int r = lr + 32*rp;
      #pragma unroll
      for (int q = 0; q < 4; ++q) {
        int kg = k0 + lk + 8*q;
        As[lk+8*q][r] = (kg < FF) ? __bfloat162float(encout[(size_t)(r0+r)*FF + kg]) : 0.0f;
      }
    }
    #pragma unroll
    for (int rp = 0; rp < 2; ++rp) {
      int cl = lr + 32*rp;
      int cc = c0 + cl;
      #pragma unroll
      for (int q = 0; q < 4; ++q) {
        int kg = k0 + lk + 8*q;
        float v = 0.0f;
        if (kg < FF) {
          v = (cc < NG) ? decWih[(size_t)cc*(FF+2) + 2 + kg]
                        : attW[(size_t)(cc - NG)*(FF+HH) + HH + kg];
        }
        Ws[lk+8*q][cl] = v;
      }
    }
    __syncthreads();
    for (int kk = 0; kk < 32; ++kk) {
      float4 a0 = *(const float4*)&As[kk][ty*8];
      float4 a1v = *(const float4*)&As[kk][ty*8 + 4];
      float4 w = *(const float4*)&Ws[kk][tx*4];
      float av[8] = {a0.x,a0.y,a0.z,a0.w,a1v.x,a1v.y,a1v.z,a1v.w};
      float wv[4] = {w.x,w.y,w.z,w.w};
      #pragma unroll
      for (int i = 0; i < 8; ++i)
        #pragma unroll
        for (int j = 0; j < 4; ++j)
          acc[i][j] = fmaf(av[i], wv[j], acc[i][j]);
    }
    __syncthreads();
  }
  bool isAtt = (c0 >= NG);
  #pragma unroll
  for (int i = 0; i < 8; ++i) {
    int rg = r0 + ty*8 + i;
    if (!isAtt) {
      float4 r4 = {acc[i][0], acc[i][1], acc[i][2], acc[i][3]};
      *(float4*)&encWp[(size_t)rg*NG + c0 + tx*4] = r4;
    } else {
      int j0 = tx*4;
      float4 r4 = {acc[i][0]+attb[j0], acc[i][1]+attb[j0+1],
                   acc[i][2]+attb[j0+2], acc[i][3]+attb[j0+3]};
      *(float4*)&encA[(size_t)rg*HH + j0] = r4;
    }
  }
}

// ---------------- K5: y_h init, decoded[:,T-1], y_loss td=0 ----------------
__global__ __launch_bounds__(256) void k_yh0(
    const float* __restrict__ h, const float* __restrict__ outW,
    const float* __restrict__ outb, const float* __restrict__ labels,
    const float* __restrict__ masksy, float* __restrict__ out,
    float* __restrict__ yh, double* __restrict__ acc)
{
  int b = blockIdx.x*256 + threadIdx.x;
  float y0 = outb[0], y1 = outb[1];
  const float* hb = h + (size_t)b*HH;
  for (int j = 0; j < HH; ++j) {
    float hv = hb[j];
    y0 = fmaf(hv, outW[j], y0);
    y1 = fmaf(hv, outW[HH+j], y1);
  }
  size_t lo = ((size_t)b*TT + (TT-1))*2;
  float l0 = labels[lo], l1 = labels[lo+1];
  float m0 = masksy[lo], m1 = masksy[lo+1];
  float d0 = (y0-l0)*m0, d1 = (y1-l1)*m1;
  out[OUT_DEC + lo]   = rnd6(l0*m0 + y0*(1.0f-m0));
  out[OUT_DEC + lo+1] = rnd6(l1*m1 + y1*(1.0f-m1));
  yh[b*2]   = y0;
  yh[b*2+1] = y1;
  acc2_block(d0*d0 + d1*d1, m0+m1, &acc[10], &acc[15]);
}

// ---------------- K6: decoder step (one wave per batch row) ----------------
__global__ __launch_bounds__(256) void k_dec(
    const float* __restrict__ labels, const float* __restrict__ masksy,
    const float* __restrict__ decWih, const float* __restrict__ decWhh,
    const float* __restrict__ decb, const float* __restrict__ attW,
    const float* __restrict__ attv, const float* __restrict__ outW,
    const float* __restrict__ outb, float* __restrict__ h, float* __restrict__ c,
    float* __restrict__ yh, const float* __restrict__ encWp,
    const float* __restrict__ encA, float* __restrict__ out,
    double* __restrict__ acc, int td)
{
  __shared__ __align__(16) float aW[64][68];    // att_W[:, :64]
  __shared__ __align__(16) float wh[256][68];   // dec_Whh
  __shared__ __align__(16) float hb4[4][64];
  int tid = threadIdx.x;
  for (int p = 0; p < 16; ++p) {
    int idx = tid + p*256;
    int j = idx >> 6, k = idx & 63;
    aW[j][k] = attW[(size_t)j*(FF+HH) + k];
  }
  for (int p = 0; p < 64; ++p) {
    int idx = tid + p*256;
    int j = idx >> 6, k = idx & 63;
    wh[j][k] = decWhh[(size_t)j*HH + k];
  }
  int wid = tid >> 6, lane = tid & 63;
  int b = blockIdx.x*4 + wid;
  float hj = h[(size_t)b*HH + lane];
  float cj = c[(size_t)b*HH + lane];
  hb4[wid][lane] = hj;
  __syncthreads();

  // h_att[lane] = sum_k attW[lane,k]*h[k]
  float hatt = 0.0f;
  #pragma unroll
  for (int k4 = 0; k4 < 16; ++k4) {
    float4 w = *(const float4*)&aW[lane][k4*4];
    float4 hv = *(const float4*)&hb4[wid][k4*4];
    hatt += w.x*hv.x + w.y*hv.y + w.z*hv.z + w.w*hv.w;
  }
  // scores + softmax over s
  float sc[5];
  float vj = attv[lane];
  #pragma unroll
  for (int s = 0; s < 5; ++s) {
    float e = tanhf(hatt + encA[((size_t)b*TT + s)*HH + lane]);
    float p = e*vj;
    #pragma unroll
    for (int off = 32; off > 0; off >>= 1) p += __shfl_xor(p, off, 64);
    sc[s] = p;
  }
  float mx = fmaxf(fmaxf(fmaxf(sc[0],sc[1]),fmaxf(sc[2],sc[3])),sc[4]);
  float se = 0.0f;
  #pragma unroll
  for (int s = 0; s < 5; ++s) { sc[s] = expf(sc[s]-mx); se += sc[s]; }
  float inv = 1.0f/se;
  #pragma unroll
  for (int s = 0; s < 5; ++s) sc[s] *= inv;
  // input_y
  int tt = TT-1-td;
  size_t lo = ((size_t)b*TT + tt)*2;
  float l0 = labels[lo], l1 = labels[lo+1];
  float m0 = masksy[lo], m1 = masksy[lo+1];
  float py0 = yh[b*2], py1 = yh[b*2+1];
  float iy0 = fmaf(l0, m0, py0*(1.0f-m0));
  float iy1 = fmaf(l1, m1, py1*(1.0f-m1));
  if (lane < 2) out[OUT_DEC + lo + lane] = rnd6(lane ? iy1 : iy0);
  // gates
  float g[4];
  #pragma unroll
  for (int gi = 0; gi < 4; ++gi) {
    int jj = gi*64 + lane;
    float a = decb[jj] + iy0*decWih[(size_t)jj*(FF+2)] + iy1*decWih[(size_t)jj*(FF+2) + 1];
    #pragma unroll
    for (int s = 0; s < 5; ++s)
      a = fmaf(sc[s], encWp[((size_t)b*TT + s)*NG + jj], a);
    float aa = 0.0f;
    #pragma unroll
    for (int k4 = 0; k4 < 16; ++k4) {
      float4 w = *(const float4*)&wh[jj][k4*4];
      float4 hv = *(const float4*)&hb4[wid][k4*4];
      aa += w.x*hv.x + w.y*hv.y + w.z*hv.z + w.w*hv.w;
    }
    g[gi] = a + aa;
  }
  float cn = sigm(g[1])*cj + sigm(g[0])*tanhf(g[2]);
  float hn = sigm(g[3])*tanhf(cn);
  c[(size_t)b*HH + lane] = cn;
  h[(size_t)b*HH + lane] = hn;
  float p0 = hn*outW[lane], p1 = hn*outW[HH+lane];
  #pragma unroll
  for (int off = 32; off > 0; off >>= 1) {
    p0 += __shfl_xor(p0, off, 64);
    p1 += __shfl_xor(p1, off, 64);
  }
  float ny0 = p0 + outb[0], ny1 = p1 + outb[1];
  if (lane == 0) { yh[b*2] = ny0; yh[b*2+1] = ny1; }
  float d0 = (ny0-l0)*m0, d1 = (ny1-l1)*m1;
  float sl  = (lane==0) ? (d0*d0 + d1*d1) : 0.0f;
  float smk = (lane==0) ? (m0+m1) : 0.0f;
  acc2_block(sl, smk, &acc[10+td], &acc[15+td]);
}

// ---------------- K7: finalize loss ----------------
__global__ void k_loss(const double* __restrict__ acc, float* __restrict__ out)
{
  if (threadIdx.x == 0 && blockIdx.x == 0) {
    double xl = 0.0, yl = 0.0;
    for (int t = 0; t < 5; ++t)
      xl += acc[t] / ((double)BB*FF) / (acc[5+t] + 1e-5);
    for (int d = 0; d < 5; ++d)
      yl += acc[10+d] / ((double)BB*2) / (acc[15+d] + 1e-5);
    out[0] = (float)((xl + yl) / 5.0);
  }
}

extern "C" void kernel_launch(void* const* d_in, const int* in_sizes, int n_in,
                              void* d_out, int out_size, void* d_ws, size_t ws_size,
                              hipStream_t stream)
{
  const float* values = (const float*)d_in[0];
  const float* masks  = (const float*)d_in[1];
  const float* deltas = (const float*)d_in[2];
  const float* labels = (const float*)d_in[3];
  const float* masksy = (const float*)d_in[4];
  const float* tdW    = (const float*)d_in[5];
  const float* tdb    = (const float*)d_in[6];
  const float* histW  = (const float*)d_in[7];
  const float* histb  = (const float*)d_in[8];
  const float* encWt  = (const float*)d_in[9];
  const float* encb   = (const float*)d_in[10];
  const float* rnnWih = (const float*)d_in[11];
  const float* rnnWhh = (const float*)d_in[12];
  const float* rnnb   = (const float*)d_in[13];
  const float* decWih = (const float*)d_in[14];
  const float* decWhh = (const float*)d_in[15];
  const float* decb   = (const float*)d_in[16];
  const float* attW   = (const float*)d_in[17];
  const float* attb   = (const float*)d_in[18];
  const float* attv   = (const float*)d_in[19];
  const float* outW   = (const float*)d_in[20];
  const float* outb   = (const float*)d_in[21];
  float* out = (float*)d_out;
  char* ws = (char*)d_ws;
  double* acc = (double*)ws;
  float* h     = (float*)(ws + H_OFF);
  float* c     = (float*)(ws + C_OFF);
  float* yh    = (float*)(ws + YH_OFF);
  float* gates = (float*)(ws + GATES_OFF);
  float* encA  = (float*)(ws + ENCATT_OFF);
  float* encWp = (float*)(ws + ENCW_OFF);
  __hip_bfloat16* encout = (__hip_bfloat16*)(ws + ENCOUT_OFF);

  (void)hipMemsetAsync(d_ws, 0, ZERO_BYTES, stream);

  for (int t = 0; t < TT; ++t) {
    k_gamma<<<BB/32, 256, 0, stream>>>(deltas, tdW, tdb, h, t);
    k_xh_enc<<<dim3(BB/64, 15), 256, 0, stream>>>(values, masks, histW, histb,
                                                  encWt, encb, h, out, encout, acc, t);
    k_gates<<<dim3(BB/64, 2), 256, 0, stream>>>(out, masks, h, rnnWih, rnnWhh,
                                                rnnb, gates, t);
    k_lstm<<<BB*HH/256, 256, 0, stream>>>(gates, h, c);
  }
  k_proj<<<dim3(BB*TT/128, 5), 256, 0, stream>>>(encout, decWih, attW, attb, encWp, encA);
  k_yh0<<<BB/256, 256, 0, stream>>>(h, outW, outb, labels, masksy, out, yh, acc);
  for (int td = 1; td < TT; ++td) {
    k_dec<<<BB/4, 256, 0, stream>>>(labels, masksy, decWih, decWhh, decb, attW,
                                    attv, outW, outb, h, c, yh, encWp, encA, out, acc, td);
  }
  k_loss<<<1, 1, 0, stream>>>(acc, out);
}

// Round 4
// 1489.560 us; speedup vs baseline: 2.5829x; 2.5829x over previous
//
#include <hip/hip_runtime.h>
#include <hip/hip_bf16.h>

#define BB 8192
#define TT 5
#define FF 923
#define HH 64
#define NG 256    // 4*H
#define KP 1920   // padded gates K: [xc 0..922][pad][m 924..1846][pad][h 1848..1911][pad]
#define OFF_M 924
#define OFF_H 1848
#define ELD 928   // encout row stride (bf16, 16B aligned)
#define PKP 960   // proj padded K

#define OUT_IMP ((size_t)1)
#define OUT_DEC ((size_t)1 + (size_t)BB*TT*FF)

// ---- workspace layout (bytes) ----
#define H_OFF      ((size_t)256)
#define C_OFF      (H_OFF + (size_t)2097152)
#define YH_OFF     (C_OFF + (size_t)2097152)
#define UNION_OFF  (YH_OFF + (size_t)65536)
// encoder-phase view of union:
#define GATES_OFF  UNION_OFF
#define G_OFF      (UNION_OFF + (size_t)8388608)
#define ABF_OFF    (G_OFF + (size_t)10485760)
// decoder-phase view of union (written by k_proj AFTER encoder done):
#define ENCW_OFF   UNION_OFF
#define ENCA_OFF   (UNION_OFF + (size_t)41943040)
#define RWB_OFF    (UNION_OFF + (size_t)52428800)
#define PWB_OFF    (RWB_OFF + (size_t)983040)
#define ENCOUT_OFF (PWB_OFF + (size_t)614400)
#define ZERO_BYTES ((size_t)4194560)   // acc + h + c

typedef unsigned short u16;
typedef __bf16 bf16_8 __attribute__((ext_vector_type(8)));
typedef float  f32_4  __attribute__((ext_vector_type(4)));
typedef u16    u16_8  __attribute__((ext_vector_type(8)));

__device__ __forceinline__ float sigm(float x){ return 1.0f/(1.0f+expf(-x)); }
__device__ __forceinline__ float rnd6(float x){ return rintf(x*1.0e6f)/1.0e6f; }
__device__ __forceinline__ u16 bf16u(float x){
  __hip_bfloat16 b = __float2bfloat16(x);
  return __builtin_bit_cast(u16, b);
}

__device__ __forceinline__ void acc2_block(float s1, float s2, double* a1, double* a2){
  #pragma unroll
  for (int off = 32; off > 0; off >>= 1){
    s1 += __shfl_xor(s1, off, 64);
    s2 += __shfl_xor(s2, off, 64);
  }
  __shared__ float r1[4], r2[4];
  int tid = threadIdx.x;
  if ((tid & 63) == 0){ r1[tid>>6] = s1; r2[tid>>6] = s2; }
  __syncthreads();
  if (tid == 0){
    atomicAdd(a1, (double)r1[0]+(double)r1[1]+(double)r1[2]+(double)r1[3]);
    atomicAdd(a2, (double)r2[0]+(double)r2[1]+(double)r2[2]+(double)r2[3]);
  }
}

// ---------------- P0: weight bf16 conversion + A_bf16 h-region zero ----------------
// flat grid: E1=256*1920 rnnW, E2=320*960 projW, E3=8192*64 zero h region
__global__ __launch_bounds__(256) void k_prep(
    const float* __restrict__ rnnWih, const float* __restrict__ rnnWhh,
    const float* __restrict__ decWih, const float* __restrict__ attW,
    u16* __restrict__ rnnWb, u16* __restrict__ projWb, u16* __restrict__ Abf)
{
  const int E1 = 256*1920, E2 = 320*960;
  int idx = blockIdx.x*256 + threadIdx.x;
  if (idx < E1) {
    int n = idx / 1920, k = idx % 1920;
    float v = 0.0f;
    if (k < 923)                    v = rnnWih[(size_t)n*1846 + k];
    else if (k >= 924 && k < 1847)  v = rnnWih[(size_t)n*1846 + (k-1)];
    else if (k >= 1848 && k < 1912) v = rnnWhh[(size_t)n*64 + (k-1848)];
    rnnWb[idx] = bf16u(v);
  } else if (idx < E1 + E2) {
    int j = idx - E1;
    int n = j / 960, k = j % 960;
    float v = 0.0f;
    if (k < 923)
      v = (n < NG) ? decWih[(size_t)n*(FF+2) + 2 + k]
                   : attW[(size_t)(n-NG)*(FF+HH) + HH + k];
    projWb[j] = bf16u(v);
  } else {
    int j = idx - E1 - E2;   // < 8192*64
    int b = j >> 6, u = j & 63;
    Abf[(size_t)b*KP + OFF_H + u] = 0;
  }
}

// ---------------- P1: G[(b*T+t)][64] = exp(-relu(deltas @ tdW^T + tdb)) ----------------
// BM=64, BN=64, BK=32; grid 640
__global__ __launch_bounds__(256) void k_gammaAll(
    const float* __restrict__ deltas, const float* __restrict__ tdW,
    const float* __restrict__ tdb, float* __restrict__ G)
{
  __shared__ __align__(16) float As[32][68];   // [k][row]
  __shared__ __align__(16) float Ws[32][68];   // [k][col]
  int tid = threadIdx.x;
  int r0 = blockIdx.x*64;
  int lk = tid & 7, lr = tid >> 3;
  int tx = tid & 15, ty = tid >> 4;
  float acc[4][4] = {};
  for (int k0 = 0; k0 < FF; k0 += 32) {
    #pragma unroll
    for (int rp = 0; rp < 2; ++rp) {
      int r = lr + 32*rp;
      #pragma unroll
      for (int q = 0; q < 4; ++q) {
        int gk = k0 + lk + 8*q;
        As[lk+8*q][r] = (gk < FF) ? deltas[(size_t)(r0+r)*FF + gk] : 0.0f;
        Ws[lk+8*q][r] = (gk < FF) ? tdW[(size_t)r*FF + gk] : 0.0f;
      }
    }
    __syncthreads();
    for (int kk = 0; kk < 32; ++kk) {
      float4 a = *(const float4*)&As[kk][ty*4];
      float4 w = *(const float4*)&Ws[kk][tx*4];
      float av[4] = {a.x,a.y,a.z,a.w};
      float wv[4] = {w.x,w.y,w.z,w.w};
      #pragma unroll
      for (int i = 0; i < 4; ++i)
        #pragma unroll
        for (int j = 0; j < 4; ++j)
          acc[i][j] = fmaf(av[i], wv[j], acc[i][j]);
    }
    __syncthreads();
  }
  #pragma unroll
  for (int i = 0; i < 4; ++i)
    #pragma unroll
    for (int j = 0; j < 4; ++j) {
      int col = tx*4 + j;
      G[(size_t)(r0 + ty*4 + i)*HH + col] = expf(-fmaxf(acc[i][j] + tdb[col], 0.0f));
    }
}

// ---------------- K2: x_h & enc, x_c -> out + A_bf16, enc -> encout bf16, loss ----------------
__global__ __launch_bounds__(256) void k_xh_enc(
    const float* __restrict__ values, const float* __restrict__ masks,
    const float* __restrict__ histW, const float* __restrict__ histb,
    const float* __restrict__ encWt, const float* __restrict__ encb,
    const float* __restrict__ h, float* __restrict__ out,
    u16* __restrict__ Abf, u16* __restrict__ encout,
    double* __restrict__ acc, int t)
{
  __shared__ __align__(16) float hs[64][68];
  __shared__ __align__(16) float W1[64][68];
  __shared__ __align__(16) float W2[64][68];
  int tid = threadIdx.x;
  int b0 = blockIdx.x*64;
  int c0 = blockIdx.y*64;
  for (int p = 0; p < 16; ++p) {
    int idx = tid + p*256;
    int r = idx >> 6, k = idx & 63;
    hs[k][r] = h[(size_t)(b0+r)*HH + k];
    int cc = c0 + r;
    W1[k][r] = (cc < FF) ? histW[(size_t)cc*HH + k] : 0.0f;
    W2[k][r] = (cc < FF) ? encWt[(size_t)cc*HH + k] : 0.0f;
  }
  __syncthreads();
  int tx = tid & 15, ty = tid >> 4;
  float a1[4][4] = {}, a2[4][4] = {};
  for (int k = 0; k < 64; ++k) {
    float4 av4 = *(const float4*)&hs[k][ty*4];
    float4 w1v = *(const float4*)&W1[k][tx*4];
    float4 w2v = *(const float4*)&W2[k][tx*4];
    float av[4] = {av4.x, av4.y, av4.z, av4.w};
    float w1a[4] = {w1v.x, w1v.y, w1v.z, w1v.w};
    float w2a[4] = {w2v.x, w2v.y, w2v.z, w2v.w};
    #pragma unroll
    for (int i = 0; i < 4; ++i)
      #pragma unroll
      for (int j = 0; j < 4; ++j) {
        a1[i][j] = fmaf(av[i], w1a[j], a1[i][j]);
        a2[i][j] = fmaf(av[i], w2a[j], a2[i][j]);
      }
  }
  float s1 = 0.0f, sm = 0.0f;
  #pragma unroll
  for (int i = 0; i < 4; ++i)
    #pragma unroll
    for (int j = 0; j < 4; ++j) {
      int col = c0 + tx*4 + j;
      int row = b0 + ty*4 + i;
      if (col < FF) {
        float xh = a1[i][j] + histb[col];
        size_t off = ((size_t)row*TT + t)*FF + col;
        float x = values[off], m = masks[off];
        float xc = m*x + (1.0f - m)*xh;
        out[OUT_IMP + off] = rnd6(xc);
        Abf[(size_t)row*KP + col] = bf16u(xc);
        Abf[(size_t)row*KP + OFF_M + col] = bf16u(m);
        float e = tanhf(a2[i][j] + encb[col]) * m;
        encout[((size_t)row*TT + t)*ELD + col] = bf16u(e);
        float d = x - xh;
        s1 += m*d*d;
        sm += m;
      }
    }
  acc2_block(s1, sm, &acc[t], &acc[5+t]);
}

// ---------------- K3a: gates MFMA GEMM: [8192 x 1920] bf16 @ [256 x 1920]^T ----------------
// 64x64 tiles, grid (128,4), 4 waves each 32x32
__global__ __launch_bounds__(256) void k_gates_mfma(
    const u16* __restrict__ A, const u16* __restrict__ W,
    const float* __restrict__ bias, float* __restrict__ gates)
{
  __shared__ __align__(16) u16 As[64*64];
  __shared__ __align__(16) u16 Bs[64*64];
  int tid = threadIdx.x;
  int m0 = blockIdx.x*64, n0 = blockIdx.y*64;
  int srow = tid >> 2, sseg = tid & 3;
  int wid = tid >> 6, lane = tid & 63;
  int wr = (wid >> 1)*32, wc = (wid & 1)*32;
  int l15 = lane & 15, lk8 = (lane >> 4)*8;
  f32_4 acc[2][2] = {};
  const u16* Ag = A + (size_t)(m0+srow)*KP + sseg*16;
  const u16* Wg = W + (size_t)(n0+srow)*KP + sseg*16;
  char* AsB = (char*)As;
  char* BsB = (char*)Bs;
  int wb = srow*128 + sseg*32;
  int swz = (srow & 7) << 4;
  for (int k0 = 0; k0 < KP; k0 += 64) {
    u16_8 a0 = *(const u16_8*)(Ag + k0);
    u16_8 a1 = *(const u16_8*)(Ag + k0 + 8);
    u16_8 b0 = *(const u16_8*)(Wg + k0);
    u16_8 b1 = *(const u16_8*)(Wg + k0 + 8);
    *(u16_8*)(AsB + ((wb     ) ^ swz)) = a0;
    *(u16_8*)(AsB + ((wb + 16) ^ swz)) = a1;
    *(u16_8*)(BsB + ((wb     ) ^ swz)) = b0;
    *(u16_8*)(BsB + ((wb + 16) ^ swz)) = b1;
    __syncthreads();
    #pragma unroll
    for (int kk = 0; kk < 64; kk += 32) {
      bf16_8 av[2], bv[2];
      #pragma unroll
      for (int mi = 0; mi < 2; ++mi) {
        int r = wr + mi*16 + l15;
        av[mi] = *(const bf16_8*)(AsB + ((r*128 + (kk+lk8)*2) ^ ((r&7)<<4)));
      }
      #pragma unroll
      for (int ni = 0; ni < 2; ++ni) {
        int cc = wc + ni*16 + l15;
        bv[ni] = *(const bf16_8*)(BsB + ((cc*128 + (kk+lk8)*2) ^ ((cc&7)<<4)));
      }
      #pragma unroll
      for (int mi = 0; mi < 2; ++mi)
        #pragma unroll
        for (int ni = 0; ni < 2; ++ni)
          acc[mi][ni] = __builtin_amdgcn_mfma_f32_16x16x32_bf16(av[mi], bv[ni], acc[mi][ni], 0, 0, 0);
    }
    __syncthreads();
  }
  #pragma unroll
  for (int mi = 0; mi < 2; ++mi)
    #pragma unroll
    for (int ni = 0; ni < 2; ++ni) {
      int col = n0 + wc + ni*16 + l15;
      float bb = bias[col];
      #pragma unroll
      for (int r = 0; r < 4; ++r) {
        int row = m0 + wr + mi*16 + (lane>>4)*4 + r;
        gates[(size_t)row*NG + col] = acc[mi][ni][r] + bb;
      }
    }
}

// ---------------- K4: proj MFMA GEMM: [40960 x 928] bf16 @ [320 x 960]^T ----------------
// grid (640, 5)
__global__ __launch_bounds__(256) void k_proj_mfma(
    const u16* __restrict__ A, const u16* __restrict__ W,
    const float* __restrict__ attb,
    float* __restrict__ encWp, float* __restrict__ encA)
{
  __shared__ __align__(16) u16 As[64*64];
  __shared__ __align__(16) u16 Bs[64*64];
  int tid = threadIdx.x;
  int m0 = blockIdx.x*64, n0 = blockIdx.y*64;
  int srow = tid >> 2, sseg = tid & 3;
  int wid = tid >> 6, lane = tid & 63;
  int wr = (wid >> 1)*32, wc = (wid & 1)*32;
  int l15 = lane & 15, lk8 = (lane >> 4)*8;
  f32_4 acc[2][2] = {};
  const u16* Ag = A + (size_t)(m0+srow)*ELD + sseg*16;
  const u16* Wg = W + (size_t)(n0+srow)*PKP + sseg*16;
  char* AsB = (char*)As;
  char* BsB = (char*)Bs;
  int wb = srow*128 + sseg*32;
  int swz = (srow & 7) << 4;
  for (int k0 = 0; k0 < PKP; k0 += 64) {
    u16_8 a0 = *(const u16_8*)(Ag + k0);
    u16_8 a1 = *(const u16_8*)(Ag + k0 + 8);
    u16_8 b0 = *(const u16_8*)(Wg + k0);
    u16_8 b1 = *(const u16_8*)(Wg + k0 + 8);
    *(u16_8*)(AsB + ((wb     ) ^ swz)) = a0;
    *(u16_8*)(AsB + ((wb + 16) ^ swz)) = a1;
    *(u16_8*)(BsB + ((wb     ) ^ swz)) = b0;
    *(u16_8*)(BsB + ((wb + 16) ^ swz)) = b1;
    __syncthreads();
    #pragma unroll
    for (int kk = 0; kk < 64; kk += 32) {
      bf16_8 av[2], bv[2];
      #pragma unroll
      for (int mi = 0; mi < 2; ++mi) {
        int r = wr + mi*16 + l15;
        av[mi] = *(const bf16_8*)(AsB + ((r*128 + (kk+lk8)*2) ^ ((r&7)<<4)));
      }
      #pragma unroll
      for (int ni = 0; ni < 2; ++ni) {
        int cc = wc + ni*16 + l15;
        bv[ni] = *(const bf16_8*)(BsB + ((cc*128 + (kk+lk8)*2) ^ ((cc&7)<<4)));
      }
      #pragma unroll
      for (int mi = 0; mi < 2; ++mi)
        #pragma unroll
        for (int ni = 0; ni < 2; ++ni)
          acc[mi][ni] = __builtin_amdgcn_mfma_f32_16x16x32_bf16(av[mi], bv[ni], acc[mi][ni], 0, 0, 0);
    }
    __syncthreads();
  }
  #pragma unroll
  for (int mi = 0; mi < 2; ++mi)
    #pragma unroll
    for (int ni = 0; ni < 2; ++ni) {
      int col = n0 + wc + ni*16 + l15;
      if (col < NG) {
        #pragma unroll
        for (int r = 0; r < 4; ++r) {
          int row = m0 + wr + mi*16 + (lane>>4)*4 + r;
          encWp[(size_t)row*NG + col] = acc[mi][ni][r];
        }
      } else {
        float bb = attb[col - NG];
        #pragma unroll
        for (int r = 0; r < 4; ++r) {
          int row = m0 + wr + mi*16 + (lane>>4)*4 + r;
          encA[(size_t)row*HH + (col - NG)] = acc[mi][ni][r] + bb;
        }
      }
    }
}

// ---------------- K3b: LSTM pointwise + fused next-step gamma + bf16 h ----------------
__global__ __launch_bounds__(256) void k_lstm(
    const float* __restrict__ gates, float* __restrict__ h, float* __restrict__ c,
    const float* __restrict__ G, u16* __restrict__ Abf, int t)
{
  int idx = blockIdx.x*256 + threadIdx.x;
  int b = idx >> 6, u = idx & 63;
  const float* g = gates + (size_t)b*NG;
  float gi = g[u], gf = g[64+u], gg = g[128+u], go = g[192+u];
  float cn = sigm(gf)*c[idx] + sigm(gi)*tanhf(gg);
  float hn = sigm(go)*tanhf(cn);
  c[idx] = cn;
  float hs = hn;
  if (t < TT-1) hs *= G[((size_t)b*TT + t + 1)*HH + u];
  h[idx] = hs;
  Abf[(size_t)b*KP + OFF_H + u] = bf16u(hs);
}

// ---------------- K5: y_h init, decoded[:,T-1], y_loss td=0 ----------------
__global__ __launch_bounds__(256) void k_yh0(
    const float* __restrict__ h, const float* __restrict__ outW,
    const float* __restrict__ outb, const float* __restrict__ labels,
    const float* __restrict__ masksy, float* __restrict__ out,
    float* __restrict__ yh, double* __restrict__ acc)
{
  int b = blockIdx.x*256 + threadIdx.x;
  float y0 = outb[0], y1 = outb[1];
  const float* hb = h + (size_t)b*HH;
  for (int j = 0; j < HH; ++j) {
    float hv = hb[j];
    y0 = fmaf(hv, outW[j], y0);
    y1 = fmaf(hv, outW[HH+j], y1);
  }
  size_t lo = ((size_t)b*TT + (TT-1))*2;
  float l0 = labels[lo], l1 = labels[lo+1];
  float m0 = masksy[lo], m1 = masksy[lo+1];
  float d0 = (y0-l0)*m0, d1 = (y1-l1)*m1;
  out[OUT_DEC + lo]   = rnd6(l0*m0 + y0*(1.0f-m0));
  out[OUT_DEC + lo+1] = rnd6(l1*m1 + y1*(1.0f-m1));
  yh[b*2]   = y0;
  yh[b*2+1] = y1;
  acc2_block(d0*d0 + d1*d1, m0+m1, &acc[10], &acc[15]);
}

// ---------------- K6: decoder step (one wave per batch row) ----------------
__global__ __launch_bounds__(256) void k_dec(
    const float* __restrict__ labels, const float* __restrict__ masksy,
    const float* __restrict__ decWih, const float* __restrict__ decWhh,
    const float* __restrict__ decb, const float* __restrict__ attW,
    const float* __restrict__ attv, const float* __restrict__ outW,
    const float* __restrict__ outb, float* __restrict__ h, float* __restrict__ c,
    float* __restrict__ yh, const float* __restrict__ encWp,
    const float* __restrict__ encA, float* __restrict__ out,
    double* __restrict__ acc, int td)
{
  __shared__ __align__(16) float aW[64][68];
  __shared__ __align__(16) float wh[256][68];
  __shared__ __align__(16) float hb4[4][64];
  int tid = threadIdx.x;
  for (int p = 0; p < 16; ++p) {
    int idx = tid + p*256;
    int j = idx >> 6, k = idx & 63;
    aW[j][k] = attW[(size_t)j*(FF+HH) + k];
  }
  for (int p = 0; p < 64; ++p) {
    int idx = tid + p*256;
    int j = idx >> 6, k = idx & 63;
    wh[j][k] = decWhh[(size_t)j*HH + k];
  }
  int wid = tid >> 6, lane = tid & 63;
  int b = blockIdx.x*4 + wid;
  float hj = h[(size_t)b*HH + lane];
  float cj = c[(size_t)b*HH + lane];
  hb4[wid][lane] = hj;
  __syncthreads();

  float hatt = 0.0f;
  #pragma unroll
  for (int k4 = 0; k4 < 16; ++k4) {
    float4 w = *(const float4*)&aW[lane][k4*4];
    float4 hv = *(const float4*)&hb4[wid][k4*4];
    hatt += w.x*hv.x + w.y*hv.y + w.z*hv.z + w.w*hv.w;
  }
  float sc[5];
  float vj = attv[lane];
  #pragma unroll
  for (int s = 0; s < 5; ++s) {
    float e = tanhf(hatt + encA[((size_t)b*TT + s)*HH + lane]);
    float p = e*vj;
    #pragma unroll
    for (int off = 32; off > 0; off >>= 1) p += __shfl_xor(p, off, 64);
    sc[s] = p;
  }
  float mx = fmaxf(fmaxf(fmaxf(sc[0],sc[1]),fmaxf(sc[2],sc[3])),sc[4]);
  float se = 0.0f;
  #pragma unroll
  for (int s = 0; s < 5; ++s) { sc[s] = expf(sc[s]-mx); se += sc[s]; }
  float inv = 1.0f/se;
  #pragma unroll
  for (int s = 0; s < 5; ++s) sc[s] *= inv;
  int tt = TT-1-td;
  size_t lo = ((size_t)b*TT + tt)*2;
  float l0 = labels[lo], l1 = labels[lo+1];
  float m0 = masksy[lo], m1 = masksy[lo+1];
  float py0 = yh[b*2], py1 = yh[b*2+1];
  float iy0 = fmaf(l0, m0, py0*(1.0f-m0));
  float iy1 = fmaf(l1, m1, py1*(1.0f-m1));
  if (lane < 2) out[OUT_DEC + lo + lane] = rnd6(lane ? iy1 : iy0);
  float g[4];
  #pragma unroll
  for (int gi = 0; gi < 4; ++gi) {
    int jj = gi*64 + lane;
    float a = decb[jj] + iy0*decWih[(size_t)jj*(FF+2)] + iy1*decWih[(size_t)jj*(FF+2) + 1];
    #pragma unroll
    for (int s = 0; s < 5; ++s)
      a = fmaf(sc[s], encWp[((size_t)b*TT + s)*NG + jj], a);
    float aa = 0.0f;
    #pragma unroll
    for (int k4 = 0; k4 < 16; ++k4) {
      float4 w = *(const float4*)&wh[jj][k4*4];
      float4 hv = *(const float4*)&hb4[wid][k4*4];
      aa += w.x*hv.x + w.y*hv.y + w.z*hv.z + w.w*hv.w;
    }
    g[gi] = a + aa;
  }
  float cn = sigm(g[1])*cj + sigm(g[0])*tanhf(g[2]);
  float hn = sigm(g[3])*tanhf(cn);
  c[(size_t)b*HH + lane] = cn;
  h[(size_t)b*HH + lane] = hn;
  float p0 = hn*outW[lane], p1 = hn*outW[HH+lane];
  #pragma unroll
  for (int off = 32; off > 0; off >>= 1) {
    p0 += __shfl_xor(p0, off, 64);
    p1 += __shfl_xor(p1, off, 64);
  }
  float ny0 = p0 + outb[0], ny1 = p1 + outb[1];
  if (lane == 0) { yh[b*2] = ny0; yh[b*2+1] = ny1; }
  float d0 = (ny0-l0)*m0, d1 = (ny1-l1)*m1;
  float sl  = (lane==0) ? (d0*d0 + d1*d1) : 0.0f;
  float smk = (lane==0) ? (m0+m1) : 0.0f;
  acc2_block(sl, smk, &acc[10+td], &acc[15+td]);
}

// ---------------- K7: finalize loss ----------------
__global__ void k_loss(const double* __restrict__ acc, float* __restrict__ out)
{
  if (threadIdx.x == 0 && blockIdx.x == 0) {
    double xl = 0.0, yl = 0.0;
    for (int t = 0; t < 5; ++t)
      xl += acc[t] / ((double)BB*FF) / (acc[5+t] + 1e-5);
    for (int d = 0; d < 5; ++d)
      yl += acc[10+d] / ((double)BB*2) / (acc[15+d] + 1e-5);
    out[0] = (float)((xl + yl) / 5.0);
  }
}

extern "C" void kernel_launch(void* const* d_in, const int* in_sizes, int n_in,
                              void* d_out, int out_size, void* d_ws, size_t ws_size,
                              hipStream_t stream)
{
  const float* values = (const float*)d_in[0];
  const float* masks  = (const float*)d_in[1];
  const float* deltas = (const float*)d_in[2];
  const float* labels = (const float*)d_in[3];
  const float* masksy = (const float*)d_in[4];
  const float* tdW    = (const float*)d_in[5];
  const float* tdb    = (const float*)d_in[6];
  const float* histW  = (const float*)d_in[7];
  const float* histb  = (const float*)d_in[8];
  const float* encWt  = (const float*)d_in[9];
  const float* encb   = (const float*)d_in[10];
  const float* rnnWih = (const float*)d_in[11];
  const float* rnnWhh = (const float*)d_in[12];
  const float* rnnb   = (const float*)d_in[13];
  const float* decWih = (const float*)d_in[14];
  const float* decWhh = (const float*)d_in[15];
  const float* decb   = (const float*)d_in[16];
  const float* attW   = (const float*)d_in[17];
  const float* attb   = (const float*)d_in[18];
  const float* attv   = (const float*)d_in[19];
  const float* outW   = (const float*)d_in[20];
  const float* outb   = (const float*)d_in[21];
  float* out = (float*)d_out;
  char* ws = (char*)d_ws;
  double* acc = (double*)ws;
  float* h      = (float*)(ws + H_OFF);
  float* c      = (float*)(ws + C_OFF);
  float* yh     = (float*)(ws + YH_OFF);
  float* gates  = (float*)(ws + GATES_OFF);
  float* G      = (float*)(ws + G_OFF);
  u16*   Abf    = (u16*)(ws + ABF_OFF);
  float* encWp  = (float*)(ws + ENCW_OFF);
  float* encA   = (float*)(ws + ENCA_OFF);
  u16*   rnnWb  = (u16*)(ws + RWB_OFF);
  u16*   projWb = (u16*)(ws + PWB_OFF);
  u16*   encout = (u16*)(ws + ENCOUT_OFF);

  (void)hipMemsetAsync(d_ws, 0, ZERO_BYTES, stream);

  k_prep<<<5168, 256, 0, stream>>>(rnnWih, rnnWhh, decWih, attW, rnnWb, projWb, Abf);
  k_gammaAll<<<640, 256, 0, stream>>>(deltas, tdW, tdb, G);

  for (int t = 0; t < TT; ++t) {
    k_xh_enc<<<dim3(BB/64, 15), 256, 0, stream>>>(values, masks, histW, histb,
                                                  encWt, encb, h, out, Abf, encout, acc, t);
    k_gates_mfma<<<dim3(BB/64, 4), 256, 0, stream>>>(Abf, rnnWb, rnnb, gates);
    k_lstm<<<BB*HH/256, 256, 0, stream>>>(gates, h, c, G, Abf, t);
  }
  k_proj_mfma<<<dim3(BB*TT/64, 5), 256, 0, stream>>>(encout, projWb, attb, encWp, encA);
  k_yh0<<<BB/256, 256, 0, stream>>>(h, outW, outb, labels, masksy, out, yh, acc);
  for (int td = 1; td < TT; ++td) {
    k_dec<<<BB/4, 256, 0, stream>>>(labels, masksy, decWih, decWhh, decb, attW,
                                    attv, outW, outb, h, c, yh, encWp, encA, out, acc, td);
  }
  k_loss<<<1, 1, 0, stream>>>(acc, out);
}

// Round 5
// 1396.173 us; speedup vs baseline: 2.7557x; 1.0669x over previous
//
#include <hip/hip_runtime.h>
#include <hip/hip_bf16.h>

#define BB 8192
#define TT 5
#define FF 923
#define HH 64
#define NG 256    // 4*H
#define KP 1920   // padded gates K: [xc 0..922][pad][m 924..1846][pad][h 1848..1911][pad]
#define OFF_M 924
#define OFF_H 1848
#define ELD 928   // encout row stride (bf16, 16B aligned)
#define PKP 960   // proj padded K
#define GKP 960   // gamma padded K

#define OUT_IMP ((size_t)1)
#define OUT_DEC ((size_t)1 + (size_t)BB*TT*FF)

// ---- workspace layout (bytes) ----
#define H_OFF      ((size_t)256)
#define C_OFF      (H_OFF + (size_t)2097152)
#define YH_OFF     (C_OFF + (size_t)2097152)
#define UNION_OFF  (YH_OFF + (size_t)65536)
// encoder-phase view of union:
#define GATES_OFF  UNION_OFF
#define G_OFF      (UNION_OFF + (size_t)8388608)
#define ABF_OFF    (G_OFF + (size_t)10485760)
#define TDWB_OFF   (UNION_OFF + (size_t)50331648)   // after Abf (ends exactly here)
#define W1B_OFF    (TDWB_OFF + (size_t)122880)
#define W2B_OFF    (W1B_OFF + (size_t)122880)
// decoder-phase view of union (written by k_proj AFTER encoder done):
#define ENCW_OFF   UNION_OFF
#define ENCA_OFF   (UNION_OFF + (size_t)41943040)
#define RWB_OFF    (UNION_OFF + (size_t)52428800)
#define PWB_OFF    (RWB_OFF + (size_t)983040)
#define ENCOUT_OFF (PWB_OFF + (size_t)614400)
#define ZERO_BYTES ((size_t)4194560)   // acc + h + c

typedef unsigned short u16;
typedef __bf16 bf16_8 __attribute__((ext_vector_type(8)));
typedef float  f32_4  __attribute__((ext_vector_type(4)));
typedef u16    u16_8  __attribute__((ext_vector_type(8)));

__device__ __forceinline__ float sigm(float x){ return 1.0f/(1.0f+expf(-x)); }
__device__ __forceinline__ float rnd6(float x){ return rintf(x*1.0e6f)/1.0e6f; }
__device__ __forceinline__ u16 bf16u(float x){
  __hip_bfloat16 b = __float2bfloat16(x);
  return __builtin_bit_cast(u16, b);
}

__device__ __forceinline__ void acc2_block(float s1, float s2, double* a1, double* a2){
  #pragma unroll
  for (int off = 32; off > 0; off >>= 1){
    s1 += __shfl_xor(s1, off, 64);
    s2 += __shfl_xor(s2, off, 64);
  }
  __shared__ float r1[4], r2[4];
  int tid = threadIdx.x;
  if ((tid & 63) == 0){ r1[tid>>6] = s1; r2[tid>>6] = s2; }
  __syncthreads();
  if (tid == 0){
    atomicAdd(a1, (double)r1[0]+(double)r1[1]+(double)r1[2]+(double)r1[3]);
    atomicAdd(a2, (double)r2[0]+(double)r2[1]+(double)r2[2]+(double)r2[3]);
  }
}

// ---------------- P0: weight bf16 conversions + A_bf16 h-region zero ----------------
__global__ __launch_bounds__(256) void k_prep(
    const float* __restrict__ rnnWih, const float* __restrict__ rnnWhh,
    const float* __restrict__ decWih, const float* __restrict__ attW,
    const float* __restrict__ tdW, const float* __restrict__ histW,
    const float* __restrict__ encWt,
    u16* __restrict__ rnnWb, u16* __restrict__ projWb, u16* __restrict__ Abf,
    u16* __restrict__ tdWb, u16* __restrict__ W1b, u16* __restrict__ W2b)
{
  const int E1 = 256*1920, E2 = 320*960, E3 = 8192*64, E4 = 64*960, E5 = 960*64;
  int idx = blockIdx.x*256 + threadIdx.x;
  if (idx < E1) {
    int n = idx / 1920, k = idx % 1920;
    float v = 0.0f;
    if (k < 923)                    v = rnnWih[(size_t)n*1846 + k];
    else if (k >= 924 && k < 1847)  v = rnnWih[(size_t)n*1846 + (k-1)];
    else if (k >= 1848 && k < 1912) v = rnnWhh[(size_t)n*64 + (k-1848)];
    rnnWb[idx] = bf16u(v);
  } else if ((idx -= E1) < E2) {
    int n = idx / 960, k = idx % 960;
    float v = 0.0f;
    if (k < 923)
      v = (n < NG) ? decWih[(size_t)n*(FF+2) + 2 + k]
                   : attW[(size_t)(n-NG)*(FF+HH) + HH + k];
    projWb[idx] = bf16u(v);
  } else if ((idx -= E2) < E3) {
    int b = idx >> 6, u = idx & 63;
    Abf[(size_t)b*KP + OFF_H + u] = 0;
  } else if ((idx -= E3) < E4) {
    int n = idx / 960, k = idx % 960;
    tdWb[idx] = (k < FF) ? bf16u(tdW[(size_t)n*FF + k]) : (u16)0;
  } else if ((idx -= E4) < E5) {
    int r = idx >> 6, k = idx & 63;
    W1b[idx] = (r < FF) ? bf16u(histW[(size_t)r*HH + k]) : (u16)0;
  } else {
    idx -= E5;
    int r = idx >> 6, k = idx & 63;
    W2b[idx] = (r < FF) ? bf16u(encWt[(size_t)r*HH + k]) : (u16)0;
  }
}

// ---------------- P1: G = exp(-relu(deltas @ tdW^T + tdb)) via MFMA ----------------
// M=40960 (grid 640), N=64, K=960; in-register fp32->bf16 conversion of deltas
__global__ __launch_bounds__(256) void k_gamma_mfma(
    const float* __restrict__ deltas, const u16* __restrict__ tdWb,
    const float* __restrict__ tdb, float* __restrict__ G)
{
  __shared__ __align__(16) u16 As[64*64];
  __shared__ __align__(16) u16 Bs[64*64];
  int tid = threadIdx.x;
  int m0 = blockIdx.x*64;
  int srow = tid >> 2, sseg = tid & 3;
  int wid = tid >> 6, lane = tid & 63;
  int wr = (wid >> 1)*32, wc = (wid & 1)*32;
  int l15 = lane & 15, lk8 = (lane >> 4)*8;
  f32_4 acc[2][2] = {};
  const float* Dg = deltas + (size_t)(m0+srow)*FF;
  const u16* Wg = tdWb + (size_t)srow*GKP + sseg*16;
  char* AsB = (char*)As;
  char* BsB = (char*)Bs;
  int wb = srow*128 + sseg*32;
  int swz = (srow & 7) << 4;
  for (int k0 = 0; k0 < GKP; k0 += 64) {
    int kb = k0 + sseg*16;
    u16_8 a0, a1;
    #pragma unroll
    for (int j = 0; j < 8; ++j) a0[j] = (kb+j < FF) ? bf16u(Dg[kb+j]) : (u16)0;
    #pragma unroll
    for (int j = 0; j < 8; ++j) a1[j] = (kb+8+j < FF) ? bf16u(Dg[kb+8+j]) : (u16)0;
    u16_8 b0 = *(const u16_8*)(Wg + k0);
    u16_8 b1 = *(const u16_8*)(Wg + k0 + 8);
    *(u16_8*)(AsB + ((wb     ) ^ swz)) = a0;
    *(u16_8*)(AsB + ((wb + 16) ^ swz)) = a1;
    *(u16_8*)(BsB + ((wb     ) ^ swz)) = b0;
    *(u16_8*)(BsB + ((wb + 16) ^ swz)) = b1;
    __syncthreads();
    #pragma unroll
    for (int kk = 0; kk < 64; kk += 32) {
      bf16_8 av[2], bv[2];
      #pragma unroll
      for (int mi = 0; mi < 2; ++mi) {
        int r = wr + mi*16 + l15;
        av[mi] = *(const bf16_8*)(AsB + ((r*128 + (kk+lk8)*2) ^ ((r&7)<<4)));
      }
      #pragma unroll
      for (int ni = 0; ni < 2; ++ni) {
        int cc = wc + ni*16 + l15;
        bv[ni] = *(const bf16_8*)(BsB + ((cc*128 + (kk+lk8)*2) ^ ((cc&7)<<4)));
      }
      #pragma unroll
      for (int mi = 0; mi < 2; ++mi)
        #pragma unroll
        for (int ni = 0; ni < 2; ++ni)
          acc[mi][ni] = __builtin_amdgcn_mfma_f32_16x16x32_bf16(av[mi], bv[ni], acc[mi][ni], 0, 0, 0);
    }
    __syncthreads();
  }
  #pragma unroll
  for (int mi = 0; mi < 2; ++mi)
    #pragma unroll
    for (int ni = 0; ni < 2; ++ni) {
      int col = wc + ni*16 + l15;
      float bb = tdb[col];
      #pragma unroll
      for (int r = 0; r < 4; ++r) {
        int row = m0 + wr + mi*16 + (lane>>4)*4 + r;
        G[(size_t)row*HH + col] = expf(-fmaxf(acc[mi][ni][r] + bb, 0.0f));
      }
    }
}

// ---------------- K2: x_h & enc via MFMA (K=64), fused epilogue ----------------
// grid (128, 15): 64-row x 64-col tiles
__global__ __launch_bounds__(256) void k_xh_enc_mfma(
    const float* __restrict__ values, const float* __restrict__ masks,
    const u16* __restrict__ W1b, const u16* __restrict__ W2b,
    const float* __restrict__ histb, const float* __restrict__ encb,
    float* __restrict__ out, u16* __restrict__ Abf, u16* __restrict__ encout,
    double* __restrict__ acc, int t)
{
  __shared__ __align__(16) u16 As[64*64];
  __shared__ __align__(16) u16 B1s[64*64];
  __shared__ __align__(16) u16 B2s[64*64];
  int tid = threadIdx.x;
  int m0 = blockIdx.x*64, c0 = blockIdx.y*64;
  int srow = tid >> 2, sseg = tid & 3;
  int wid = tid >> 6, lane = tid & 63;
  int wr = (wid >> 1)*32, wc = (wid & 1)*32;
  int l15 = lane & 15, lk8 = (lane >> 4)*8;
  f32_4 a1c[2][2] = {}, a2c[2][2] = {};
  char* AsB = (char*)As;
  char* B1B = (char*)B1s;
  char* B2B = (char*)B2s;
  int wb = srow*128 + sseg*32;
  int swz = (srow & 7) << 4;
  {
    const u16* Ag = Abf + (size_t)(m0+srow)*KP + OFF_H + sseg*16;
    const u16* W1g = W1b + (size_t)(c0+srow)*HH + sseg*16;
    const u16* W2g = W2b + (size_t)(c0+srow)*HH + sseg*16;
    u16_8 a0 = *(const u16_8*)(Ag);
    u16_8 a1 = *(const u16_8*)(Ag + 8);
    u16_8 w10 = *(const u16_8*)(W1g);
    u16_8 w11 = *(const u16_8*)(W1g + 8);
    u16_8 w20 = *(const u16_8*)(W2g);
    u16_8 w21 = *(const u16_8*)(W2g + 8);
    *(u16_8*)(AsB + ((wb     ) ^ swz)) = a0;
    *(u16_8*)(AsB + ((wb + 16) ^ swz)) = a1;
    *(u16_8*)(B1B + ((wb     ) ^ swz)) = w10;
    *(u16_8*)(B1B + ((wb + 16) ^ swz)) = w11;
    *(u16_8*)(B2B + ((wb     ) ^ swz)) = w20;
    *(u16_8*)(B2B + ((wb + 16) ^ swz)) = w21;
  }
  __syncthreads();
  #pragma unroll
  for (int kk = 0; kk < 64; kk += 32) {
    bf16_8 av[2], b1v[2], b2v[2];
    #pragma unroll
    for (int mi = 0; mi < 2; ++mi) {
      int r = wr + mi*16 + l15;
      av[mi] = *(const bf16_8*)(AsB + ((r*128 + (kk+lk8)*2) ^ ((r&7)<<4)));
    }
    #pragma unroll
    for (int ni = 0; ni < 2; ++ni) {
      int cc = wc + ni*16 + l15;
      b1v[ni] = *(const bf16_8*)(B1B + ((cc*128 + (kk+lk8)*2) ^ ((cc&7)<<4)));
      b2v[ni] = *(const bf16_8*)(B2B + ((cc*128 + (kk+lk8)*2) ^ ((cc&7)<<4)));
    }
    #pragma unroll
    for (int mi = 0; mi < 2; ++mi)
      #pragma unroll
      for (int ni = 0; ni < 2; ++ni) {
        a1c[mi][ni] = __builtin_amdgcn_mfma_f32_16x16x32_bf16(av[mi], b1v[ni], a1c[mi][ni], 0, 0, 0);
        a2c[mi][ni] = __builtin_amdgcn_mfma_f32_16x16x32_bf16(av[mi], b2v[ni], a2c[mi][ni], 0, 0, 0);
      }
  }
  float s1 = 0.0f, sm = 0.0f;
  #pragma unroll
  for (int mi = 0; mi < 2; ++mi)
    #pragma unroll
    for (int ni = 0; ni < 2; ++ni) {
      int col = c0 + wc + ni*16 + l15;
      if (col < FF) {
        float hb = histb[col], eb = encb[col];
        #pragma unroll
        for (int r = 0; r < 4; ++r) {
          int row = m0 + wr + mi*16 + (lane>>4)*4 + r;
          size_t off = ((size_t)row*TT + t)*FF + col;
          float xh = a1c[mi][ni][r] + hb;
          float x = values[off], m = masks[off];
          float xc = m*x + (1.0f - m)*xh;
          out[OUT_IMP + off] = rnd6(xc);
          Abf[(size_t)row*KP + col] = bf16u(xc);
          Abf[(size_t)row*KP + OFF_M + col] = bf16u(m);
          float e = tanhf(a2c[mi][ni][r] + eb) * m;
          encout[((size_t)row*TT + t)*ELD + col] = bf16u(e);
          float d = x - xh;
          s1 += m*d*d;
          sm += m;
        }
      }
    }
  acc2_block(s1, sm, &acc[t], &acc[5+t]);
}

// ---------------- K3a: gates MFMA GEMM: [8192 x 1920] bf16 @ [256 x 1920]^T ----------------
__global__ __launch_bounds__(256) void k_gates_mfma(
    const u16* __restrict__ A, const u16* __restrict__ W,
    const float* __restrict__ bias, float* __restrict__ gates)
{
  __shared__ __align__(16) u16 As[64*64];
  __shared__ __align__(16) u16 Bs[64*64];
  int tid = threadIdx.x;
  int m0 = blockIdx.x*64, n0 = blockIdx.y*64;
  int srow = tid >> 2, sseg = tid & 3;
  int wid = tid >> 6, lane = tid & 63;
  int wr = (wid >> 1)*32, wc = (wid & 1)*32;
  int l15 = lane & 15, lk8 = (lane >> 4)*8;
  f32_4 acc[2][2] = {};
  const u16* Ag = A + (size_t)(m0+srow)*KP + sseg*16;
  const u16* Wg = W + (size_t)(n0+srow)*KP + sseg*16;
  char* AsB = (char*)As;
  char* BsB = (char*)Bs;
  int wb = srow*128 + sseg*32;
  int swz = (srow & 7) << 4;
  for (int k0 = 0; k0 < KP; k0 += 64) {
    u16_8 a0 = *(const u16_8*)(Ag + k0);
    u16_8 a1 = *(const u16_8*)(Ag + k0 + 8);
    u16_8 b0 = *(const u16_8*)(Wg + k0);
    u16_8 b1 = *(const u16_8*)(Wg + k0 + 8);
    *(u16_8*)(AsB + ((wb     ) ^ swz)) = a0;
    *(u16_8*)(AsB + ((wb + 16) ^ swz)) = a1;
    *(u16_8*)(BsB + ((wb     ) ^ swz)) = b0;
    *(u16_8*)(BsB + ((wb + 16) ^ swz)) = b1;
    __syncthreads();
    #pragma unroll
    for (int kk = 0; kk < 64; kk += 32) {
      bf16_8 av[2], bv[2];
      #pragma unroll
      for (int mi = 0; mi < 2; ++mi) {
        int r = wr + mi*16 + l15;
        av[mi] = *(const bf16_8*)(AsB + ((r*128 + (kk+lk8)*2) ^ ((r&7)<<4)));
      }
      #pragma unroll
      for (int ni = 0; ni < 2; ++ni) {
        int cc = wc + ni*16 + l15;
        bv[ni] = *(const bf16_8*)(BsB + ((cc*128 + (kk+lk8)*2) ^ ((cc&7)<<4)));
      }
      #pragma unroll
      for (int mi = 0; mi < 2; ++mi)
        #pragma unroll
        for (int ni = 0; ni < 2; ++ni)
          acc[mi][ni] = __builtin_amdgcn_mfma_f32_16x16x32_bf16(av[mi], bv[ni], acc[mi][ni], 0, 0, 0);
    }
    __syncthreads();
  }
  #pragma unroll
  for (int mi = 0; mi < 2; ++mi)
    #pragma unroll
    for (int ni = 0; ni < 2; ++ni) {
      int col = n0 + wc + ni*16 + l15;
      float bb = bias[col];
      #pragma unroll
      for (int r = 0; r < 4; ++r) {
        int row = m0 + wr + mi*16 + (lane>>4)*4 + r;
        gates[(size_t)row*NG + col] = acc[mi][ni][r] + bb;
      }
    }
}

// ---------------- K4: proj MFMA GEMM: [40960 x 928] bf16 @ [320 x 960]^T ----------------
__global__ __launch_bounds__(256) void k_proj_mfma(
    const u16* __restrict__ A, const u16* __restrict__ W,
    const float* __restrict__ attb,
    float* __restrict__ encWp, float* __restrict__ encA)
{
  __shared__ __align__(16) u16 As[64*64];
  __shared__ __align__(16) u16 Bs[64*64];
  int tid = threadIdx.x;
  int m0 = blockIdx.x*64, n0 = blockIdx.y*64;
  int srow = tid >> 2, sseg = tid & 3;
  int wid = tid >> 6, lane = tid & 63;
  int wr = (wid >> 1)*32, wc = (wid & 1)*32;
  int l15 = lane & 15, lk8 = (lane >> 4)*8;
  f32_4 acc[2][2] = {};
  const u16* Ag = A + (size_t)(m0+srow)*ELD + sseg*16;
  const u16* Wg = W + (size_t)(n0+srow)*PKP + sseg*16;
  char* AsB = (char*)As;
  char* BsB = (char*)Bs;
  int wb = srow*128 + sseg*32;
  int swz = (srow & 7) << 4;
  for (int k0 = 0; k0 < PKP; k0 += 64) {
    u16_8 a0, a1;
    if (k0 < ELD) {
      a0 = *(const u16_8*)(Ag + k0);
      a1 = *(const u16_8*)(Ag + k0 + 8);
    } else {
      a0 = (u16_8)0; a1 = (u16_8)0;
    }
    u16_8 b0 = *(const u16_8*)(Wg + k0);
    u16_8 b1 = *(const u16_8*)(Wg + k0 + 8);
    *(u16_8*)(AsB + ((wb     ) ^ swz)) = a0;
    *(u16_8*)(AsB + ((wb + 16) ^ swz)) = a1;
    *(u16_8*)(BsB + ((wb     ) ^ swz)) = b0;
    *(u16_8*)(BsB + ((wb + 16) ^ swz)) = b1;
    __syncthreads();
    #pragma unroll
    for (int kk = 0; kk < 64; kk += 32) {
      bf16_8 av[2], bv[2];
      #pragma unroll
      for (int mi = 0; mi < 2; ++mi) {
        int r = wr + mi*16 + l15;
        av[mi] = *(const bf16_8*)(AsB + ((r*128 + (kk+lk8)*2) ^ ((r&7)<<4)));
      }
      #pragma unroll
      for (int ni = 0; ni < 2; ++ni) {
        int cc = wc + ni*16 + l15;
        bv[ni] = *(const bf16_8*)(BsB + ((cc*128 + (kk+lk8)*2) ^ ((cc&7)<<4)));
      }
      #pragma unroll
      for (int mi = 0; mi < 2; ++mi)
        #pragma unroll
        for (int ni = 0; ni < 2; ++ni)
          acc[mi][ni] = __builtin_amdgcn_mfma_f32_16x16x32_bf16(av[mi], bv[ni], acc[mi][ni], 0, 0, 0);
    }
    __syncthreads();
  }
  #pragma unroll
  for (int mi = 0; mi < 2; ++mi)
    #pragma unroll
    for (int ni = 0; ni < 2; ++ni) {
      int col = n0 + wc + ni*16 + l15;
      if (col < NG) {
        #pragma unroll
        for (int r = 0; r < 4; ++r) {
          int row = m0 + wr + mi*16 + (lane>>4)*4 + r;
          encWp[(size_t)row*NG + col] = acc[mi][ni][r];
        }
      } else {
        float bb = attb[col - NG];
        #pragma unroll
        for (int r = 0; r < 4; ++r) {
          int row = m0 + wr + mi*16 + (lane>>4)*4 + r;
          encA[(size_t)row*HH + (col - NG)] = acc[mi][ni][r] + bb;
        }
      }
    }
}

// ---------------- K3b: LSTM pointwise + fused next-step gamma + bf16 h ----------------
__global__ __launch_bounds__(256) void k_lstm(
    const float* __restrict__ gates, float* __restrict__ h, float* __restrict__ c,
    const float* __restrict__ G, u16* __restrict__ Abf, int t)
{
  int idx = blockIdx.x*256 + threadIdx.x;
  int b = idx >> 6, u = idx & 63;
  const float* g = gates + (size_t)b*NG;
  float gi = g[u], gf = g[64+u], gg = g[128+u], go = g[192+u];
  float cn = sigm(gf)*c[idx] + sigm(gi)*tanhf(gg);
  float hn = sigm(go)*tanhf(cn);
  c[idx] = cn;
  float hs = hn;
  if (t < TT-1) hs *= G[((size_t)b*TT + t + 1)*HH + u];
  h[idx] = hs;
  Abf[(size_t)b*KP + OFF_H + u] = bf16u(hs);
}

// ---------------- K5: y_h init, decoded[:,T-1], y_loss td=0 ----------------
__global__ __launch_bounds__(256) void k_yh0(
    const float* __restrict__ h, const float* __restrict__ outW,
    const float* __restrict__ outb, const float* __restrict__ labels,
    const float* __restrict__ masksy, float* __restrict__ out,
    float* __restrict__ yh, double* __restrict__ acc)
{
  int b = blockIdx.x*256 + threadIdx.x;
  float y0 = outb[0], y1 = outb[1];
  const float* hb = h + (size_t)b*HH;
  for (int j = 0; j < HH; ++j) {
    float hv = hb[j];
    y0 = fmaf(hv, outW[j], y0);
    y1 = fmaf(hv, outW[HH+j], y1);
  }
  size_t lo = ((size_t)b*TT + (TT-1))*2;
  float l0 = labels[lo], l1 = labels[lo+1];
  float m0 = masksy[lo], m1 = masksy[lo+1];
  float d0 = (y0-l0)*m0, d1 = (y1-l1)*m1;
  out[OUT_DEC + lo]   = rnd6(l0*m0 + y0*(1.0f-m0));
  out[OUT_DEC + lo+1] = rnd6(l1*m1 + y1*(1.0f-m1));
  yh[b*2]   = y0;
  yh[b*2+1] = y1;
  acc2_block(d0*d0 + d1*d1, m0+m1, &acc[10], &acc[15]);
}

// ---------------- K6: decoder step (one wave per batch row) ----------------
__global__ __launch_bounds__(256) void k_dec(
    const float* __restrict__ labels, const float* __restrict__ masksy,
    const float* __restrict__ decWih, const float* __restrict__ decWhh,
    const float* __restrict__ decb, const float* __restrict__ attW,
    const float* __restrict__ attv, const float* __restrict__ outW,
    const float* __restrict__ outb, float* __restrict__ h, float* __restrict__ c,
    float* __restrict__ yh, const float* __restrict__ encWp,
    const float* __restrict__ encA, float* __restrict__ out,
    double* __restrict__ acc, int td)
{
  __shared__ __align__(16) float aW[64][68];
  __shared__ __align__(16) float wh[256][68];
  __shared__ __align__(16) float hb4[4][64];
  int tid = threadIdx.x;
  for (int p = 0; p < 16; ++p) {
    int idx = tid + p*256;
    int j = idx >> 6, k = idx & 63;
    aW[j][k] = attW[(size_t)j*(FF+HH) + k];
  }
  for (int p = 0; p < 64; ++p) {
    int idx = tid + p*256;
    int j = idx >> 6, k = idx & 63;
    wh[j][k] = decWhh[(size_t)j*HH + k];
  }
  int wid = tid >> 6, lane = tid & 63;
  int b = blockIdx.x*4 + wid;
  float hj = h[(size_t)b*HH + lane];
  float cj = c[(size_t)b*HH + lane];
  hb4[wid][lane] = hj;
  __syncthreads();

  float hatt = 0.0f;
  #pragma unroll
  for (int k4 = 0; k4 < 16; ++k4) {
    float4 w = *(const float4*)&aW[lane][k4*4];
    float4 hv = *(const float4*)&hb4[wid][k4*4];
    hatt += w.x*hv.x + w.y*hv.y + w.z*hv.z + w.w*hv.w;
  }
  float sc[5];
  float vj = attv[lane];
  #pragma unroll
  for (int s = 0; s < 5; ++s) {
    float e = tanhf(hatt + encA[((size_t)b*TT + s)*HH + lane]);
    float p = e*vj;
    #pragma unroll
    for (int off = 32; off > 0; off >>= 1) p += __shfl_xor(p, off, 64);
    sc[s] = p;
  }
  float mx = fmaxf(fmaxf(fmaxf(sc[0],sc[1]),fmaxf(sc[2],sc[3])),sc[4]);
  float se = 0.0f;
  #pragma unroll
  for (int s = 0; s < 5; ++s) { sc[s] = expf(sc[s]-mx); se += sc[s]; }
  float inv = 1.0f/se;
  #pragma unroll
  for (int s = 0; s < 5; ++s) sc[s] *= inv;
  int tt = TT-1-td;
  size_t lo = ((size_t)b*TT + tt)*2;
  float l0 = labels[lo], l1 = labels[lo+1];
  float m0 = masksy[lo], m1 = masksy[lo+1];
  float py0 = yh[b*2], py1 = yh[b*2+1];
  float iy0 = fmaf(l0, m0, py0*(1.0f-m0));
  float iy1 = fmaf(l1, m1, py1*(1.0f-m1));
  if (lane < 2) out[OUT_DEC + lo + lane] = rnd6(lane ? iy1 : iy0);
  float g[4];
  #pragma unroll
  for (int gi = 0; gi < 4; ++gi) {
    int jj = gi*64 + lane;
    float a = decb[jj] + iy0*decWih[(size_t)jj*(FF+2)] + iy1*decWih[(size_t)jj*(FF+2) + 1];
    #pragma unroll
    for (int s = 0; s < 5; ++s)
      a = fmaf(sc[s], encWp[((size_t)b*TT + s)*NG + jj], a);
    float aa = 0.0f;
    #pragma unroll
    for (int k4 = 0; k4 < 16; ++k4) {
      float4 w = *(const float4*)&wh[jj][k4*4];
      float4 hv = *(const float4*)&hb4[wid][k4*4];
      aa += w.x*hv.x + w.y*hv.y + w.z*hv.z + w.w*hv.w;
    }
    g[gi] = a + aa;
  }
  float cn = sigm(g[1])*cj + sigm(g[0])*tanhf(g[2]);
  float hn = sigm(g[3])*tanhf(cn);
  c[(size_t)b*HH + lane] = cn;
  h[(size_t)b*HH + lane] = hn;
  float p0 = hn*outW[lane], p1 = hn*outW[HH+lane];
  #pragma unroll
  for (int off = 32; off > 0; off >>= 1) {
    p0 += __shfl_xor(p0, off, 64);
    p1 += __shfl_xor(p1, off, 64);
  }
  float ny0 = p0 + outb[0], ny1 = p1 + outb[1];
  if (lane == 0) { yh[b*2] = ny0; yh[b*2+1] = ny1; }
  float d0 = (ny0-l0)*m0, d1 = (ny1-l1)*m1;
  float sl  = (lane==0) ? (d0*d0 + d1*d1) : 0.0f;
  float smk = (lane==0) ? (m0+m1) : 0.0f;
  acc2_block(sl, smk, &acc[10+td], &acc[15+td]);
}

// ---------------- K7: finalize loss ----------------
__global__ void k_loss(const double* __restrict__ acc, float* __restrict__ out)
{
  if (threadIdx.x == 0 && blockIdx.x == 0) {
    double xl = 0.0, yl = 0.0;
    for (int t = 0; t < 5; ++t)
      xl += acc[t] / ((double)BB*FF) / (acc[5+t] + 1e-5);
    for (int d = 0; d < 5; ++d)
      yl += acc[10+d] / ((double)BB*2) / (acc[15+d] + 1e-5);
    out[0] = (float)((xl + yl) / 5.0);
  }
}

extern "C" void kernel_launch(void* const* d_in, const int* in_sizes, int n_in,
                              void* d_out, int out_size, void* d_ws, size_t ws_size,
                              hipStream_t stream)
{
  const float* values = (const float*)d_in[0];
  const float* masks  = (const float*)d_in[1];
  const float* deltas = (const float*)d_in[2];
  const float* labels = (const float*)d_in[3];
  const float* masksy = (const float*)d_in[4];
  const float* tdW    = (const float*)d_in[5];
  const float* tdb    = (const float*)d_in[6];
  const float* histW  = (const float*)d_in[7];
  const float* histb  = (const float*)d_in[8];
  const float* encWt  = (const float*)d_in[9];
  const float* encb   = (const float*)d_in[10];
  const float* rnnWih = (const float*)d_in[11];
  const float* rnnWhh = (const float*)d_in[12];
  const float* rnnb   = (const float*)d_in[13];
  const float* decWih = (const float*)d_in[14];
  const float* decWhh = (const float*)d_in[15];
  const float* decb   = (const float*)d_in[16];
  const float* attW   = (const float*)d_in[17];
  const float* attb   = (const float*)d_in[18];
  const float* attv   = (const float*)d_in[19];
  const float* outW   = (const float*)d_in[20];
  const float* outb   = (const float*)d_in[21];
  float* out = (float*)d_out;
  char* ws = (char*)d_ws;
  double* acc = (double*)ws;
  float* h      = (float*)(ws + H_OFF);
  float* c      = (float*)(ws + C_OFF);
  float* yh     = (float*)(ws + YH_OFF);
  float* gates  = (float*)(ws + GATES_OFF);
  float* G      = (float*)(ws + G_OFF);
  u16*   Abf    = (u16*)(ws + ABF_OFF);
  u16*   tdWb   = (u16*)(ws + TDWB_OFF);
  u16*   W1b    = (u16*)(ws + W1B_OFF);
  u16*   W2b    = (u16*)(ws + W2B_OFF);
  float* encWp  = (float*)(ws + ENCW_OFF);
  float* encA   = (float*)(ws + ENCA_OFF);
  u16*   rnnWb  = (u16*)(ws + RWB_OFF);
  u16*   projWb = (u16*)(ws + PWB_OFF);
  u16*   encout = (u16*)(ws + ENCOUT_OFF);

  (void)hipMemsetAsync(d_ws, 0, ZERO_BYTES, stream);

  k_prep<<<5888, 256, 0, stream>>>(rnnWih, rnnWhh, decWih, attW, tdW, histW, encWt,
                                   rnnWb, projWb, Abf, tdWb, W1b, W2b);
  k_gamma_mfma<<<640, 256, 0, stream>>>(deltas, tdWb, tdb, G);

  for (int t = 0; t < TT; ++t) {
    k_xh_enc_mfma<<<dim3(BB/64, 15), 256, 0, stream>>>(values, masks, W1b, W2b,
                                                       histb, encb, out, Abf, encout, acc, t);
    k_gates_mfma<<<dim3(BB/64, 4), 256, 0, stream>>>(Abf, rnnWb, rnnb, gates);
    k_lstm<<<BB*HH/256, 256, 0, stream>>>(gates, h, c, G, Abf, t);
  }
  k_proj_mfma<<<dim3(BB*TT/64, 5), 256, 0, stream>>>(encout, projWb, attb, encWp, encA);
  k_yh0<<<BB/256, 256, 0, stream>>>(h, outW, outb, labels, masksy, out, yh, acc);
  for (int td = 1; td < TT; ++td) {
    k_dec<<<BB/4, 256, 0, stream>>>(labels, masksy, decWih, decWhh, decb, attW,
                                    attv, outW, outb, h, c, yh, encWp, encA, out, acc, td);
  }
  k_loss<<<1, 1, 0, stream>>>(acc, out);
}